// Round 10
// baseline (99.139 us; speedup 1.0000x reference)
//
#include <hip/hip_runtime.h>
#include <math.h>

#define CH 40
#define IMW 1024
#define TOKH (9*10*40)        // 3600 halves per token: [rr 0..8][10-slot row stride][40 ch]
#define W2T_HALVES (48*48*8)  // ws layout [kchunk 0..47][co 0..47][j 0..7]
#define Z1_OFF W2T_HALVES
#define OUTC_OFF (Z1_OFF + 40)   // 6 f32 stored after z1 (byte offset divisible by 4)
#define Y2T 768                  // f32 per token in y2 overlay: 16 pos x stride 48

typedef _Float16 v8h __attribute__((ext_vector_type(8)));
typedef _Float16 v4h __attribute__((ext_vector_type(4)));
typedef float    v4f __attribute__((ext_vector_type(4)));
typedef float    v2f __attribute__((ext_vector_type(2)));

// gelu(tanh approx) == x * sigmoid(2*0.79788456*(x+0.044715x^3)) — exact identity
__device__ __forceinline__ float gelu_fast(float x) {
    float u = 1.5957691216057308f * (x + 0.044715f * x * x * x);
    return x * __builtin_amdgcn_rcpf(1.0f + __expf(-u));
}

// ---- pre-kernel: f16 weight table + z1 + constant-position dense contribution ----
__global__ __launch_bounds__(256) void prep_kernel(
    const float* __restrict__ w2,
    const float* __restrict__ b1, const float* __restrict__ s1,
    const float* __restrict__ bb1,
    const float* __restrict__ b2, const float* __restrict__ s2,
    const float* __restrict__ bb2,
    const float* __restrict__ dw, const float* __restrict__ db,
    _Float16* __restrict__ ws)
{
    int t = threadIdx.x;
    int idx0 = blockIdx.x * 256 + t;
    for (int idx = idx0; idx < W2T_HALVES; idx += gridDim.x * 256) {
        int j   = idx & 7;
        int co  = (idx >> 3) % 48;
        int kgg = idx / (48 * 8);
        int k   = kgg * 8 + j;          // k = window*40 + ci
        float v = 0.0f;
        if (co < CH && k < 360) {
            int wi = k / 40, ci = k - wi * 40;
            v = w2[(wi * CH + ci) * CH + co];
        }
        ws[idx] = (_Float16)v;
    }
    if (blockIdx.x != 0) return;

    __shared__ float zs[40];
    __shared__ float w2sum[9][40];
    // z1 = gelu(LN(b1)) in f32
    if (t < CH) {
        float mu = 0.f, m2 = 0.f;
        for (int i = 0; i < CH; i++) mu += b1[i];
        mu /= CH;
        for (int i = 0; i < CH; i++) { float d = b1[i] - mu; m2 += d * d; }
        float rs = rsqrtf(m2 / CH + 1e-6f);
        float g = gelu_fast((b1[t] - mu) * rs * s1[t] + bb1[t]);
        zs[t] = g;
        ws[Z1_OFF + t] = (_Float16)g;
    }
    __syncthreads();
    // w2sum[win][ch] = sum_ci w2[win,ci,ch] * z1[ci]
    if (t < CH) {
        for (int wi = 0; wi < 9; wi++) {
            float s = 0.f;
            for (int ci = 0; ci < CH; ci++)
                s += w2[(wi * CH + ci) * CH + t] * zs[ci];
            w2sum[wi][t] = s;
        }
    }
    __syncthreads();
    // const positions (p>=4 || q>=4): y2c -> LN2 -> gelu -> dense, reduce to outc[6]
    if (t < 64) {
        int p = t >> 3, q = t & 7;
        float a6[6] = {0.f, 0.f, 0.f, 0.f, 0.f, 0.f};
        if (p >= 4 || q >= 4) {
            int drmax = (p == 7) ? 2 : 3;   // rr=16 is conv2 zero-pad row
            int dcmax = (q == 7) ? 2 : 3;
            float sum = 0.f;
            for (int ch = 0; ch < CH; ch++) {
                float y = b2[ch];
                for (int dr = 0; dr < drmax; dr++)
                    for (int dc = 0; dc < dcmax; dc++)
                        y += w2sum[dr * 3 + dc][ch];
                sum += y;
            }
            float mu = sum / CH;
            float var = 0.f;
            for (int ch = 0; ch < CH; ch++) {
                float y = b2[ch];
                for (int dr = 0; dr < drmax; dr++)
                    for (int dc = 0; dc < dcmax; dc++)
                        y += w2sum[dr * 3 + dc][ch];
                float d = y - mu; var += d * d;
            }
            float rs = rsqrtf(var / CH + 1e-6f);
            for (int ch = 0; ch < CH; ch++) {
                float y = b2[ch];
                for (int dr = 0; dr < drmax; dr++)
                    for (int dc = 0; dc < dcmax; dc++)
                        y += w2sum[dr * 3 + dc][ch];
                float g = gelu_fast((y - mu) * rs * s2[ch] + bb2[ch]);
                const float* wp = &dw[((p * 8 + q) * CH + ch) * 6];
                for (int k = 0; k < 6; k++) a6[k] += g * wp[k];
            }
        }
        #pragma unroll
        for (int off = 32; off > 0; off >>= 1)
            #pragma unroll
            for (int k = 0; k < 6; k++) a6[k] += __shfl_down(a6[k], off, 64);
        if (t == 0) {
            float* oc = (float*)&ws[OUTC_OFF];
            for (int k = 0; k < 6; k++) oc[k] = a6[k] + db[k];
        }
    }
}

// ---- main kernel: 2 tokens per block, real-positions-only (p<4 && q<4) conv2 ----
__global__ __launch_bounds__(256) void sgn_kernel(
    const float* __restrict__ img,
    const float* __restrict__ w1, const float* __restrict__ b1,
    const float* __restrict__ s1, const float* __restrict__ bb1,
    const float* __restrict__ b2, const float* __restrict__ s2,
    const float* __restrict__ bb2,
    const float* __restrict__ dw,
    const _Float16* __restrict__ ws,
    float* __restrict__ out)
{
    // x1h: 2 x TOKH halves = 14400 B; later overlaid by y2: 2 x Y2T f32 = 6144 B
    __shared__ __align__(16) unsigned char sbuf[2 * TOKH * 2];
    _Float16* x1h = (_Float16*)sbuf;
    float*    y2f = (float*)sbuf;
    __shared__ float img_s[2][16][16];
    __shared__ float w1t[40 * 12];
    __shared__ float p1s[120];         // b1 | s1 | bb1
    __shared__ float p2s[120];         // b2 | s2 | bb2
    __shared__ unsigned koff_s[48];

    const int t = threadIdx.x;

    int crr[2], ccc[2];
    #pragma unroll
    for (int tk = 0; tk < 2; tk++) {
        int f   = blockIdx.x * 2 + tk;
        int cfg = f >> 10;
        int ij  = f & 1023;
        int ti  = ij >> 5, tj = ij & 31;
        crr[tk] = 2 * ti + (cfg & 1);
        ccc[tk] = 2 * tj + (cfg >> 1);
    }

    // ---- Phase A ----
    {
        int r = t >> 4, c = t & 15;
        #pragma unroll
        for (int tk = 0; tk < 2; tk++)
            img_s[tk][r][c] = img[(crr[tk] * 16 + r) * IMW + ccc[tk] * 16 + c];
    }
    for (int i = t; i < 360; i += 256) {
        int k = i / 40, ch = i - k * 40;
        w1t[ch * 12 + k] = w1[i];
    }
    if (t < 120) {
        p1s[t] = (t < 40) ? b1[t] : (t < 80 ? s1[t - 40] : bb1[t - 80]);
    } else if (t >= 128 && t < 248) {
        int i = t - 128;
        p2s[i] = (i < 40) ? b2[i] : (i < 80 ? s2[i - 40] : bb2[i - 80]);
    }
    if (t < 48) {
        int s = t >> 2, kg = t & 3;
        int k0 = 32 * s + 8 * kg;
        unsigned v = 0;
        if (k0 < 360) {
            int wi = k0 / 40, ci0 = k0 - wi * 40;
            int dr = wi / 3, dc = wi - 3 * dr;
            v = (unsigned)((dr * 10 + dc) * 40 + ci0);
        }
        koff_s[t] = v;     // k>=360: koff 0 is safe (B rows are zero there)
    }
    __syncthreads();

    // ---- Phase B: conv1 + LN1 + gelu -> x1h [9][10][40]; 2 thr/pos, 20 ch ----
    {
        const int tk  = t >> 7;
        const int pos = (t >> 1) & 63;
        const int sub = t & 1;
        const int r = pos >> 3, c = pos & 7;
        float vin[9];
        #pragma unroll
        for (int dr = 0; dr < 3; dr++)
            #pragma unroll
            for (int dc = 0; dc < 3; dc++) {
                int rr = 2 * r + dr, cp = 2 * c + dc;
                vin[dr * 3 + dc] = (rr < 16 && cp < 16) ? img_s[tk][rr][cp] : 0.0f;
            }
        const int ch0 = sub * 20;
        float y[20];
        float s_own = 0.f;
        #pragma unroll
        for (int u = 0; u < 20; u++) {
            float a = p1s[ch0 + u];
            const float* wr = &w1t[(ch0 + u) * 12];
            #pragma unroll
            for (int k = 0; k < 9; k++) a += vin[k] * wr[k];
            y[u] = a; s_own += a;
        }
        s_own += __shfl_xor(s_own, 1, 64);
        float mu = s_own * (1.0f / CH);
        float v_own = 0.f;
        #pragma unroll
        for (int u = 0; u < 20; u++) { float d = y[u] - mu; v_own += d * d; }
        v_own += __shfl_xor(v_own, 1, 64);
        float rs = rsqrtf(v_own * (1.0f / CH) + 1e-6f);
        _Float16 g[20];
        #pragma unroll
        for (int u = 0; u < 20; u++) {
            int ch = ch0 + u;
            g[u] = (_Float16)gelu_fast((y[u] - mu) * rs * p1s[40 + ch] + p1s[80 + ch]);
        }
        const int base = tk * TOKH + (r * 10 + c) * 40 + ch0;
        if (sub == 0) {
            *(v8h*)&x1h[base]      = *(v8h*)&g[0];
            *(v8h*)&x1h[base + 8]  = *(v8h*)&g[8];
            *(v4h*)&x1h[base + 16] = *(v4h*)&g[16];
        } else {
            *(v4h*)&x1h[base]      = *(v4h*)&g[0];
            *(v8h*)&x1h[base + 4]  = *(v8h*)&g[4];
            *(v8h*)&x1h[base + 12] = *(v8h*)&g[12];
        }
    }
    // border fill: rr=8 row (9 pos) + cc=8 col (8 pos) per token, all = z1
    if (t < 34) {
        int tk = (t >= 17), i = t - tk * 17;
        int r = (i < 9) ? 8 : (i - 9);
        int c = (i < 9) ? i : 8;
        const v8h* zsrc = (const v8h*)&ws[Z1_OFF];
        int base = tk * TOKH + (r * 10 + c) * 40;
        *(v8h*)&x1h[base]      = zsrc[0];
        *(v8h*)&x1h[base + 8]  = zsrc[1];
        *(v8h*)&x1h[base + 16] = zsrc[2];
        *(v8h*)&x1h[base + 24] = zsrc[3];
        *(v8h*)&x1h[base + 32] = zsrc[4];
    }
    __syncthreads();

    // ---- Phase C: conv2 MFMA, M=16 real positions/token; wave n owns N-tile n ----
    v4f accA = {0,0,0,0}, accB = {0,0,0,0};
    const int wv   = t >> 6;
    const int lane = t & 63;
    if (wv < 3) {
        const int row = lane & 15;       // A-row = real position index m (p=m>>2,q=m&3)
        const int kg  = lane >> 4;
        const unsigned pbase = (unsigned)((20 * (row >> 2) + 2 * (row & 3)) * 40);
        #pragma unroll
        for (int s = 0; s < 12; s++) {
            const int kc = (s << 2) | kg;
            unsigned aoff = pbase + koff_s[kc];
            v8h a0 = *(const v8h*)&x1h[aoff];
            v8h a1 = *(const v8h*)&x1h[TOKH + aoff];
            v8h bf = *(const v8h*)&ws[(kc * 48 + wv * 16 + row) * 8];
            accA = __builtin_amdgcn_mfma_f32_16x16x32_f16(a0, bf, accA, 0, 0, 0);
            accB = __builtin_amdgcn_mfma_f32_16x16x32_f16(a1, bf, accB, 0, 0, 0);
        }
    }
    __syncthreads();   // x1h reads done; overlay y2

    if (wv < 3) {
        const int cix = lane & 15;           // channel within N-tile
        const int kg  = lane >> 4;
        if (wv < 2 || cix < 8) {             // skip padding channels 40..47
            #pragma unroll
            for (int j = 0; j < 4; j++) {
                int m = (kg << 2) | j;       // real position index
                y2f[m * 48 + wv * 16 + cix]       = accA[j];
                y2f[Y2T + m * 48 + wv * 16 + cix] = accB[j];
            }
        }
    }
    __syncthreads();

    // ---- Phase D: bias + LN2 + gelu + dense over 16 real positions; + const part ----
    if (t < 128) {
        const int tk  = t >> 6;              // wave 0 = token 0, wave 1 = token 1
        const int pos = (t >> 2) & 15;
        const int sub = t & 3;
        const int co0 = sub * 10;
        float vv[10];
        float s_own = 0.f;
        #pragma unroll
        for (int u = 0; u < 10; u++) {
            float a = y2f[tk * Y2T + pos * 48 + co0 + u] + p2s[co0 + u];
            vv[u] = a; s_own += a;
        }
        s_own += __shfl_xor(s_own, 1, 64);
        s_own += __shfl_xor(s_own, 2, 64);
        float mu = s_own * (1.0f / CH);
        float v_own = 0.f;
        #pragma unroll
        for (int u = 0; u < 10; u++) { float d = vv[u] - mu; v_own += d * d; }
        v_own += __shfl_xor(v_own, 1, 64);
        v_own += __shfl_xor(v_own, 2, 64);
        float rs = rsqrtf(v_own * (1.0f / CH) + 1e-6f);

        const int p = pos >> 2, q = pos & 3;
        const float* wp = &dw[((p * 8 + q) * CH + co0) * 6];
        float a6[6] = {0.f, 0.f, 0.f, 0.f, 0.f, 0.f};
        #pragma unroll
        for (int u = 0; u < 10; u++) {
            float gv = gelu_fast((vv[u] - mu) * rs * p2s[40 + co0 + u] + p2s[80 + co0 + u]);
            v2f w01 = *(const v2f*)&wp[u * 6];
            v2f w23 = *(const v2f*)&wp[u * 6 + 2];
            v2f w45 = *(const v2f*)&wp[u * 6 + 4];
            a6[0] += gv * w01[0]; a6[1] += gv * w01[1];
            a6[2] += gv * w23[0]; a6[3] += gv * w23[1];
            a6[4] += gv * w45[0]; a6[5] += gv * w45[1];
        }
        #pragma unroll
        for (int off = 32; off > 0; off >>= 1)
            #pragma unroll
            for (int k = 0; k < 6; k++) a6[k] += __shfl_down(a6[k], off, 64);
        if (lane == 0) {
            const float* oc = (const float*)&ws[OUTC_OFF];
            int f = blockIdx.x * 2 + tk;
            #pragma unroll
            for (int k = 0; k < 6; k++) out[f * 6 + k] = a6[k] + oc[k];
        }
    }
}

extern "C" void kernel_launch(void* const* d_in, const int* in_sizes, int n_in,
                              void* d_out, int out_size, void* d_ws, size_t ws_size,
                              hipStream_t stream) {
    const float* img = (const float*)d_in[0];
    // d_in[1] = masks: analytically redundant (mask == cell id), not read.
    const float* w1  = (const float*)d_in[2];
    const float* b1  = (const float*)d_in[3];
    const float* s1  = (const float*)d_in[4];
    const float* bb1 = (const float*)d_in[5];
    const float* w2  = (const float*)d_in[6];
    const float* b2  = (const float*)d_in[7];
    const float* s2  = (const float*)d_in[8];
    const float* bb2 = (const float*)d_in[9];
    const float* dw  = (const float*)d_in[10];
    const float* db  = (const float*)d_in[11];
    float* out = (float*)d_out;
    _Float16* ws = (_Float16*)d_ws;

    prep_kernel<<<32, 256, 0, stream>>>(w2, b1, s1, bb1, b2, s2, bb2, dw, db, ws);
    sgn_kernel<<<2048, 256, 0, stream>>>(img, w1, b1, s1, bb1,
                                         b2, s2, bb2, dw, ws, out);
}

// Round 11
// 48.296 us; speedup vs baseline: 2.0528x; 2.0528x over previous
//
#include <hip/hip_runtime.h>
#include <math.h>

#define CH 40
#define IMW 1024
#define TOKH (9*10*40)        // 3600 halves per token: [rr 0..8][10-slot row stride][40 ch]
#define W2T_HALVES (48*48*8)  // ws layout [kchunk 0..47][co 0..47][j 0..7]
#define Z1_OFF W2T_HALVES
#define OUTC_OFF (Z1_OFF + 40)   // 6 f32 stored after z1 (byte offset divisible by 4)
#define Y2T 768                  // f32 per token in y2 overlay: 16 pos x stride 48

typedef _Float16 v8h __attribute__((ext_vector_type(8)));
typedef _Float16 v4h __attribute__((ext_vector_type(4)));
typedef float    v4f __attribute__((ext_vector_type(4)));
typedef float    v2f __attribute__((ext_vector_type(2)));

// gelu(tanh approx) == x * sigmoid(2*0.79788456*(x+0.044715x^3)) — exact identity
__device__ __forceinline__ float gelu_fast(float x) {
    float u = 1.5957691216057308f * (x + 0.044715f * x * x * x);
    return x * __builtin_amdgcn_rcpf(1.0f + __expf(-u));
}

// ---- pre-kernel: f16 weight table + z1 + constant-position dense contribution ----
__global__ __launch_bounds__(256) void prep_kernel(
    const float* __restrict__ w2,
    const float* __restrict__ b1, const float* __restrict__ s1,
    const float* __restrict__ bb1,
    const float* __restrict__ b2, const float* __restrict__ s2,
    const float* __restrict__ bb2,
    const float* __restrict__ dw, const float* __restrict__ db,
    _Float16* __restrict__ ws)
{
    int t = threadIdx.x;
    int idx0 = blockIdx.x * 256 + t;
    for (int idx = idx0; idx < W2T_HALVES; idx += gridDim.x * 256) {
        int j   = idx & 7;
        int co  = (idx >> 3) % 48;
        int kgg = idx / (48 * 8);
        int k   = kgg * 8 + j;          // k = window*40 + ci
        float v = 0.0f;
        if (co < CH && k < 360) {
            int wi = k / 40, ci = k - wi * 40;
            v = w2[(wi * CH + ci) * CH + co];
        }
        ws[idx] = (_Float16)v;
    }
    if (blockIdx.x != 0) return;

    __shared__ float zs[40];
    __shared__ float w2sum[9][40];
    // z1 = gelu(LN(b1)) in f32
    if (t < CH) {
        float mu = 0.f, m2 = 0.f;
        for (int i = 0; i < CH; i++) mu += b1[i];
        mu /= CH;
        for (int i = 0; i < CH; i++) { float d = b1[i] - mu; m2 += d * d; }
        float rs = rsqrtf(m2 / CH + 1e-6f);
        float g = gelu_fast((b1[t] - mu) * rs * s1[t] + bb1[t]);
        zs[t] = g;
        ws[Z1_OFF + t] = (_Float16)g;
    }
    __syncthreads();
    // w2sum[wi][ch] = sum_ci w2[wi,ci,ch] * z1[ci]; 256 threads, coalesced over ch
    for (int idx = t; idx < 360; idx += 256) {
        int wi = idx / 40, ch = idx - wi * 40;
        float s = 0.f;
        #pragma unroll 8
        for (int ci = 0; ci < CH; ci++)
            s += w2[(wi * CH + ci) * CH + ch] * zs[ci];
        w2sum[wi][ch] = s;
    }
    __syncthreads();
    // const positions (p>=4 || q>=4): y2c -> LN2 -> gelu -> dense; single pass, y in regs
    if (t < 64) {
        int p = t >> 3, q = t & 7;
        float a6[6] = {0.f, 0.f, 0.f, 0.f, 0.f, 0.f};
        if (p >= 4 || q >= 4) {
            int drmax = (p == 7) ? 2 : 3;   // rr=16 is conv2 zero-pad row
            int dcmax = (q == 7) ? 2 : 3;
            float y[CH];
            float sum = 0.f;
            for (int ch = 0; ch < CH; ch++) {
                float v = b2[ch];
                for (int dr = 0; dr < drmax; dr++)
                    for (int dc = 0; dc < dcmax; dc++)
                        v += w2sum[dr * 3 + dc][ch];
                y[ch] = v; sum += v;
            }
            float mu = sum / CH;
            float var = 0.f;
            for (int ch = 0; ch < CH; ch++) { float d = y[ch] - mu; var += d * d; }
            float rs = rsqrtf(var / CH + 1e-6f);
            const float* wp0 = &dw[(p * 8 + q) * CH * 6];
            for (int ch = 0; ch < CH; ch++) {
                float g = gelu_fast((y[ch] - mu) * rs * s2[ch] + bb2[ch]);
                const float* wp = wp0 + ch * 6;
                #pragma unroll
                for (int k = 0; k < 6; k++) a6[k] += g * wp[k];
            }
        }
        #pragma unroll
        for (int off = 32; off > 0; off >>= 1)
            #pragma unroll
            for (int k = 0; k < 6; k++) a6[k] += __shfl_down(a6[k], off, 64);
        if (t == 0) {
            float* oc = (float*)&ws[OUTC_OFF];
            for (int k = 0; k < 6; k++) oc[k] = a6[k] + db[k];
        }
    }
}

// ---- main kernel: 2 tokens per block, real-positions-only (p<4 && q<4) conv2 ----
__global__ __launch_bounds__(256) void sgn_kernel(
    const float* __restrict__ img,
    const float* __restrict__ w1, const float* __restrict__ b1,
    const float* __restrict__ s1, const float* __restrict__ bb1,
    const float* __restrict__ b2, const float* __restrict__ s2,
    const float* __restrict__ bb2,
    const float* __restrict__ dw,
    const _Float16* __restrict__ ws,
    float* __restrict__ out)
{
    // x1h: 2 x TOKH halves = 14400 B; later overlaid by y2: 2 x Y2T f32 = 6144 B
    __shared__ __align__(16) unsigned char sbuf[2 * TOKH * 2];
    _Float16* x1h = (_Float16*)sbuf;
    float*    y2f = (float*)sbuf;
    __shared__ float img_s[2][16][16];
    __shared__ float w1t[40 * 12];
    __shared__ float p1s[120];         // b1 | s1 | bb1
    __shared__ float p2s[120];         // b2 | s2 | bb2
    __shared__ unsigned koff_s[48];

    const int t = threadIdx.x;

    int crr[2], ccc[2];
    #pragma unroll
    for (int tk = 0; tk < 2; tk++) {
        int f   = blockIdx.x * 2 + tk;
        int cfg = f >> 10;
        int ij  = f & 1023;
        int ti  = ij >> 5, tj = ij & 31;
        crr[tk] = 2 * ti + (cfg & 1);
        ccc[tk] = 2 * tj + (cfg >> 1);
    }

    // ---- Phase A ----
    {
        int r = t >> 4, c = t & 15;
        #pragma unroll
        for (int tk = 0; tk < 2; tk++)
            img_s[tk][r][c] = img[(crr[tk] * 16 + r) * IMW + ccc[tk] * 16 + c];
    }
    for (int i = t; i < 360; i += 256) {
        int k = i / 40, ch = i - k * 40;
        w1t[ch * 12 + k] = w1[i];
    }
    if (t < 120) {
        p1s[t] = (t < 40) ? b1[t] : (t < 80 ? s1[t - 40] : bb1[t - 80]);
    } else if (t >= 128 && t < 248) {
        int i = t - 128;
        p2s[i] = (i < 40) ? b2[i] : (i < 80 ? s2[i - 40] : bb2[i - 80]);
    }
    if (t < 48) {
        int s = t >> 2, kg = t & 3;
        int k0 = 32 * s + 8 * kg;
        unsigned v = 0;
        if (k0 < 360) {
            int wi = k0 / 40, ci0 = k0 - wi * 40;
            int dr = wi / 3, dc = wi - 3 * dr;
            v = (unsigned)((dr * 10 + dc) * 40 + ci0);
        }
        koff_s[t] = v;     // k>=360: koff 0 is safe (B rows are zero there)
    }
    __syncthreads();

    // ---- Phase B: conv1 + LN1 + gelu -> x1h [9][10][40]; 2 thr/pos, 20 ch ----
    {
        const int tk  = t >> 7;
        const int pos = (t >> 1) & 63;
        const int sub = t & 1;
        const int r = pos >> 3, c = pos & 7;
        float vin[9];
        #pragma unroll
        for (int dr = 0; dr < 3; dr++)
            #pragma unroll
            for (int dc = 0; dc < 3; dc++) {
                int rr = 2 * r + dr, cp = 2 * c + dc;
                vin[dr * 3 + dc] = (rr < 16 && cp < 16) ? img_s[tk][rr][cp] : 0.0f;
            }
        const int ch0 = sub * 20;
        float y[20];
        float s_own = 0.f;
        #pragma unroll
        for (int u = 0; u < 20; u++) {
            float a = p1s[ch0 + u];
            const float* wr = &w1t[(ch0 + u) * 12];
            #pragma unroll
            for (int k = 0; k < 9; k++) a += vin[k] * wr[k];
            y[u] = a; s_own += a;
        }
        s_own += __shfl_xor(s_own, 1, 64);
        float mu = s_own * (1.0f / CH);
        float v_own = 0.f;
        #pragma unroll
        for (int u = 0; u < 20; u++) { float d = y[u] - mu; v_own += d * d; }
        v_own += __shfl_xor(v_own, 1, 64);
        float rs = rsqrtf(v_own * (1.0f / CH) + 1e-6f);
        _Float16 g[20];
        #pragma unroll
        for (int u = 0; u < 20; u++) {
            int ch = ch0 + u;
            g[u] = (_Float16)gelu_fast((y[u] - mu) * rs * p1s[40 + ch] + p1s[80 + ch]);
        }
        const int base = tk * TOKH + (r * 10 + c) * 40 + ch0;
        if (sub == 0) {
            *(v8h*)&x1h[base]      = *(v8h*)&g[0];
            *(v8h*)&x1h[base + 8]  = *(v8h*)&g[8];
            *(v4h*)&x1h[base + 16] = *(v4h*)&g[16];
        } else {
            *(v4h*)&x1h[base]      = *(v4h*)&g[0];
            *(v8h*)&x1h[base + 4]  = *(v8h*)&g[4];
            *(v8h*)&x1h[base + 12] = *(v8h*)&g[12];
        }
    }
    // border fill: rr=8 row (9 pos) + cc=8 col (8 pos) per token, all = z1
    if (t < 34) {
        int tk = (t >= 17), i = t - tk * 17;
        int r = (i < 9) ? 8 : (i - 9);
        int c = (i < 9) ? i : 8;
        const v8h* zsrc = (const v8h*)&ws[Z1_OFF];
        int base = tk * TOKH + (r * 10 + c) * 40;
        *(v8h*)&x1h[base]      = zsrc[0];
        *(v8h*)&x1h[base + 8]  = zsrc[1];
        *(v8h*)&x1h[base + 16] = zsrc[2];
        *(v8h*)&x1h[base + 24] = zsrc[3];
        *(v8h*)&x1h[base + 32] = zsrc[4];
    }
    __syncthreads();

    // ---- Phase C: conv2 MFMA, M=16 real positions/token; wave n owns N-tile n ----
    v4f accA = {0,0,0,0}, accB = {0,0,0,0};
    const int wv   = t >> 6;
    const int lane = t & 63;
    if (wv < 3) {
        const int row = lane & 15;       // A-row = real position index m (p=m>>2,q=m&3)
        const int kg  = lane >> 4;
        const unsigned pbase = (unsigned)((20 * (row >> 2) + 2 * (row & 3)) * 40);
        #pragma unroll
        for (int s = 0; s < 12; s++) {
            const int kc = (s << 2) | kg;
            unsigned aoff = pbase + koff_s[kc];
            v8h a0 = *(const v8h*)&x1h[aoff];
            v8h a1 = *(const v8h*)&x1h[TOKH + aoff];
            v8h bf = *(const v8h*)&ws[(kc * 48 + wv * 16 + row) * 8];
            accA = __builtin_amdgcn_mfma_f32_16x16x32_f16(a0, bf, accA, 0, 0, 0);
            accB = __builtin_amdgcn_mfma_f32_16x16x32_f16(a1, bf, accB, 0, 0, 0);
        }
    }
    __syncthreads();   // x1h reads done; overlay y2

    if (wv < 3) {
        const int cix = lane & 15;           // channel within N-tile
        const int kg  = lane >> 4;
        if (wv < 2 || cix < 8) {             // skip padding channels 40..47
            #pragma unroll
            for (int j = 0; j < 4; j++) {
                int m = (kg << 2) | j;       // real position index
                y2f[m * 48 + wv * 16 + cix]       = accA[j];
                y2f[Y2T + m * 48 + wv * 16 + cix] = accB[j];
            }
        }
    }
    __syncthreads();

    // ---- Phase D: bias + LN2 + gelu + dense over 16 real positions; + const part ----
    if (t < 128) {
        const int tk  = t >> 6;              // wave 0 = token 0, wave 1 = token 1
        const int pos = (t >> 2) & 15;
        const int sub = t & 3;
        const int co0 = sub * 10;
        float vv[10];
        float s_own = 0.f;
        #pragma unroll
        for (int u = 0; u < 10; u++) {
            float a = y2f[tk * Y2T + pos * 48 + co0 + u] + p2s[co0 + u];
            vv[u] = a; s_own += a;
        }
        s_own += __shfl_xor(s_own, 1, 64);
        s_own += __shfl_xor(s_own, 2, 64);
        float mu = s_own * (1.0f / CH);
        float v_own = 0.f;
        #pragma unroll
        for (int u = 0; u < 10; u++) { float d = vv[u] - mu; v_own += d * d; }
        v_own += __shfl_xor(v_own, 1, 64);
        v_own += __shfl_xor(v_own, 2, 64);
        float rs = rsqrtf(v_own * (1.0f / CH) + 1e-6f);

        const int p = pos >> 2, q = pos & 3;
        const float* wp = &dw[((p * 8 + q) * CH + co0) * 6];
        float a6[6] = {0.f, 0.f, 0.f, 0.f, 0.f, 0.f};
        #pragma unroll
        for (int u = 0; u < 10; u++) {
            float gv = gelu_fast((vv[u] - mu) * rs * p2s[40 + co0 + u] + p2s[80 + co0 + u]);
            v2f w01 = *(const v2f*)&wp[u * 6];
            v2f w23 = *(const v2f*)&wp[u * 6 + 2];
            v2f w45 = *(const v2f*)&wp[u * 6 + 4];
            a6[0] += gv * w01[0]; a6[1] += gv * w01[1];
            a6[2] += gv * w23[0]; a6[3] += gv * w23[1];
            a6[4] += gv * w45[0]; a6[5] += gv * w45[1];
        }
        #pragma unroll
        for (int off = 32; off > 0; off >>= 1)
            #pragma unroll
            for (int k = 0; k < 6; k++) a6[k] += __shfl_down(a6[k], off, 64);
        if (lane == 0) {
            const float* oc = (const float*)&ws[OUTC_OFF];
            int f = blockIdx.x * 2 + tk;
            #pragma unroll
            for (int k = 0; k < 6; k++) out[f * 6 + k] = a6[k] + oc[k];
        }
    }
}

extern "C" void kernel_launch(void* const* d_in, const int* in_sizes, int n_in,
                              void* d_out, int out_size, void* d_ws, size_t ws_size,
                              hipStream_t stream) {
    const float* img = (const float*)d_in[0];
    // d_in[1] = masks: analytically redundant (mask == cell id), not read.
    const float* w1  = (const float*)d_in[2];
    const float* b1  = (const float*)d_in[3];
    const float* s1  = (const float*)d_in[4];
    const float* bb1 = (const float*)d_in[5];
    const float* w2  = (const float*)d_in[6];
    const float* b2  = (const float*)d_in[7];
    const float* s2  = (const float*)d_in[8];
    const float* bb2 = (const float*)d_in[9];
    const float* dw  = (const float*)d_in[10];
    const float* db  = (const float*)d_in[11];
    float* out = (float*)d_out;
    _Float16* ws = (_Float16*)d_ws;

    prep_kernel<<<32, 256, 0, stream>>>(w2, b1, s1, bb1, b2, s2, bb2, dw, db, ws);
    sgn_kernel<<<2048, 256, 0, stream>>>(img, w1, b1, s1, bb1,
                                         b2, s2, bb2, dw, ws, out);
}

// Round 12
// 32.181 us; speedup vs baseline: 3.0806x; 1.5007x over previous
//
#include <hip/hip_runtime.h>
#include <math.h>

#define CH 40
#define IMW 1024
#define TOKH (9*10*40)        // 3600 halves per token: [rr 0..8][10-slot row stride][40 ch]
#define W2T_HALVES (48*48*8)  // ws layout [kchunk 0..47][co 0..47][j 0..7]
#define Z1_OFF W2T_HALVES
#define OUTC_OFF (Z1_OFF + 40)   // 6 f32 stored after z1 (byte offset divisible by 4)
#define Y2T 768                  // f32 per token in y2 overlay: 16 pos x stride 48

typedef _Float16 v8h __attribute__((ext_vector_type(8)));
typedef _Float16 v4h __attribute__((ext_vector_type(4)));
typedef float    v4f __attribute__((ext_vector_type(4)));
typedef float    v2f __attribute__((ext_vector_type(2)));

// gelu(tanh approx) == x * sigmoid(2*0.79788456*(x+0.044715x^3)) — exact identity
__device__ __forceinline__ float gelu_fast(float x) {
    float u = 1.5957691216057308f * (x + 0.044715f * x * x * x);
    return x * __builtin_amdgcn_rcpf(1.0f + __expf(-u));
}

// ---- pre-kernel: f16 weight table + z1 + constant-position dense contribution ----
__global__ __launch_bounds__(256) void prep_kernel(
    const float* __restrict__ w2,
    const float* __restrict__ b1, const float* __restrict__ s1,
    const float* __restrict__ bb1,
    const float* __restrict__ b2, const float* __restrict__ s2,
    const float* __restrict__ bb2,
    const float* __restrict__ dw, const float* __restrict__ db,
    _Float16* __restrict__ ws)
{
    const int t = threadIdx.x;
    int idx0 = blockIdx.x * 256 + t;
    for (int idx = idx0; idx < W2T_HALVES; idx += gridDim.x * 256) {
        int j   = idx & 7;
        int co  = (idx >> 3) % 48;
        int kgg = idx / (48 * 8);
        int k   = kgg * 8 + j;          // k = window*40 + ci
        float v = 0.0f;
        if (co < CH && k < 360) {
            int wi = k / 40, ci = k - wi * 40;
            v = w2[(wi * CH + ci) * CH + co];
        }
        ws[idx] = (_Float16)v;
    }
    if (blockIdx.x != 0) return;

    __shared__ float zs[40];
    __shared__ float w2sum[9][40];
    __shared__ float p2l[120];          // b2 | s2 | bb2
    __shared__ float red[4][6];

    // stage b2|s2|bb2 coalesced
    if (t < 120) p2l[t] = (t < 40) ? b2[t] : (t < 80 ? s2[t - 40] : bb2[t - 80]);

    // z1 = gelu(LN(b1)): wave 1, lane-parallel, two-pass centered variance
    if (t >= 64 && t < 128) {
        int lane = t - 64;
        bool act = lane < CH;
        float bv = act ? b1[lane] : 0.f;
        float s = bv;
        #pragma unroll
        for (int m = 1; m < 64; m <<= 1) s += __shfl_xor(s, m, 64);
        float mu = s * (1.0f / CH);
        float d = act ? (bv - mu) : 0.f;
        float q = d * d;
        #pragma unroll
        for (int m = 1; m < 64; m <<= 1) q += __shfl_xor(q, m, 64);
        float rs = rsqrtf(q * (1.0f / CH) + 1e-6f);
        if (act) {
            float g = gelu_fast((bv - mu) * rs * s1[lane] + bb1[lane]);
            zs[lane] = g;
            ws[Z1_OFF + lane] = (_Float16)g;
        }
    }
    __syncthreads();

    // w2sum[wi][ch] = sum_ci w2[wi,ci,ch] * z1[ci]; 360 items / 256 threads, unrolled
    for (int idx = t; idx < 360; idx += 256) {
        int wi = idx / 40, ch = idx - wi * 40;
        float s = 0.f;
        #pragma unroll
        for (int ci = 0; ci < CH; ci++)
            s += w2[(wi * CH + ci) * CH + ch] * zs[ci];
        w2sum[wi][ch] = s;
    }
    __syncthreads();

    // const positions (p>=4 || q>=4): all 256 threads; m = t>>2, sub = t&3 (10 ch each)
    {
        const int m = t >> 2, sub = t & 3;
        const int p = m >> 3, q = m & 7;
        const int co0 = sub * 10;
        float a6[6] = {0.f, 0.f, 0.f, 0.f, 0.f, 0.f};
        if (p >= 4 || q >= 4) {
            const int drmax = (p == 7) ? 2 : 3;   // rr=16 is conv2 zero-pad row
            const int dcmax = (q == 7) ? 2 : 3;
            float vv[10];
            float s_own = 0.f;
            #pragma unroll
            for (int u = 0; u < 10; u++) {
                float v = p2l[co0 + u];
                for (int dr = 0; dr < drmax; dr++)
                    for (int dc = 0; dc < dcmax; dc++)
                        v += w2sum[dr * 3 + dc][co0 + u];
                vv[u] = v; s_own += v;
            }
            s_own += __shfl_xor(s_own, 1, 64);
            s_own += __shfl_xor(s_own, 2, 64);
            float mu = s_own * (1.0f / CH);
            float v_own = 0.f;
            #pragma unroll
            for (int u = 0; u < 10; u++) { float d = vv[u] - mu; v_own += d * d; }
            v_own += __shfl_xor(v_own, 1, 64);
            v_own += __shfl_xor(v_own, 2, 64);
            float rs = rsqrtf(v_own * (1.0f / CH) + 1e-6f);
            const float* wp = &dw[(m * CH + co0) * 6];
            #pragma unroll
            for (int u = 0; u < 10; u++) {
                float gv = gelu_fast((vv[u] - mu) * rs * p2l[40 + co0 + u] + p2l[80 + co0 + u]);
                v2f w01 = *(const v2f*)&wp[u * 6];
                v2f w23 = *(const v2f*)&wp[u * 6 + 2];
                v2f w45 = *(const v2f*)&wp[u * 6 + 4];
                a6[0] += gv * w01[0]; a6[1] += gv * w01[1];
                a6[2] += gv * w23[0]; a6[3] += gv * w23[1];
                a6[4] += gv * w45[0]; a6[5] += gv * w45[1];
            }
        }
        // block-wide reduce (real positions contributed zero)
        #pragma unroll
        for (int off = 32; off > 0; off >>= 1)
            #pragma unroll
            for (int k = 0; k < 6; k++) a6[k] += __shfl_down(a6[k], off, 64);
        int wv = t >> 6, lane = t & 63;
        if (lane == 0) {
            #pragma unroll
            for (int k = 0; k < 6; k++) red[wv][k] = a6[k];
        }
        __syncthreads();
        if (t == 0) {
            float* oc = (float*)&ws[OUTC_OFF];
            #pragma unroll
            for (int k = 0; k < 6; k++)
                oc[k] = red[0][k] + red[1][k] + red[2][k] + red[3][k] + db[k];
        }
    }
}

// ---- main kernel: 2 tokens per block, real-positions-only (p<4 && q<4) conv2 ----
__global__ __launch_bounds__(256) void sgn_kernel(
    const float* __restrict__ img,
    const float* __restrict__ w1, const float* __restrict__ b1,
    const float* __restrict__ s1, const float* __restrict__ bb1,
    const float* __restrict__ b2, const float* __restrict__ s2,
    const float* __restrict__ bb2,
    const float* __restrict__ dw,
    const _Float16* __restrict__ ws,
    float* __restrict__ out)
{
    // x1h: 2 x TOKH halves = 14400 B; later overlaid by y2: 2 x Y2T f32 = 6144 B
    __shared__ __align__(16) unsigned char sbuf[2 * TOKH * 2];
    _Float16* x1h = (_Float16*)sbuf;
    float*    y2f = (float*)sbuf;
    __shared__ float img_s[2][16][16];
    __shared__ float w1t[40 * 12];
    __shared__ float p1s[120];         // b1 | s1 | bb1
    __shared__ float p2s[120];         // b2 | s2 | bb2
    __shared__ unsigned koff_s[48];

    const int t = threadIdx.x;

    int crr[2], ccc[2];
    #pragma unroll
    for (int tk = 0; tk < 2; tk++) {
        int f   = blockIdx.x * 2 + tk;
        int cfg = f >> 10;
        int ij  = f & 1023;
        int ti  = ij >> 5, tj = ij & 31;
        crr[tk] = 2 * ti + (cfg & 1);
        ccc[tk] = 2 * tj + (cfg >> 1);
    }

    // ---- Phase A ----
    {
        int r = t >> 4, c = t & 15;
        #pragma unroll
        for (int tk = 0; tk < 2; tk++)
            img_s[tk][r][c] = img[(crr[tk] * 16 + r) * IMW + ccc[tk] * 16 + c];
    }
    for (int i = t; i < 360; i += 256) {
        int k = i / 40, ch = i - k * 40;
        w1t[ch * 12 + k] = w1[i];
    }
    if (t < 120) {
        p1s[t] = (t < 40) ? b1[t] : (t < 80 ? s1[t - 40] : bb1[t - 80]);
    } else if (t >= 128 && t < 248) {
        int i = t - 128;
        p2s[i] = (i < 40) ? b2[i] : (i < 80 ? s2[i - 40] : bb2[i - 80]);
    }
    if (t < 48) {
        int s = t >> 2, kg = t & 3;
        int k0 = 32 * s + 8 * kg;
        unsigned v = 0;
        if (k0 < 360) {
            int wi = k0 / 40, ci0 = k0 - wi * 40;
            int dr = wi / 3, dc = wi - 3 * dr;
            v = (unsigned)((dr * 10 + dc) * 40 + ci0);
        }
        koff_s[t] = v;     // k>=360: koff 0 is safe (B rows are zero there)
    }
    __syncthreads();

    // ---- Phase B: conv1 + LN1 + gelu -> x1h [9][10][40]; 2 thr/pos, 20 ch ----
    {
        const int tk  = t >> 7;
        const int pos = (t >> 1) & 63;
        const int sub = t & 1;
        const int r = pos >> 3, c = pos & 7;
        float vin[9];
        #pragma unroll
        for (int dr = 0; dr < 3; dr++)
            #pragma unroll
            for (int dc = 0; dc < 3; dc++) {
                int rr = 2 * r + dr, cp = 2 * c + dc;
                vin[dr * 3 + dc] = (rr < 16 && cp < 16) ? img_s[tk][rr][cp] : 0.0f;
            }
        const int ch0 = sub * 20;
        float y[20];
        float s_own = 0.f;
        #pragma unroll
        for (int u = 0; u < 20; u++) {
            float a = p1s[ch0 + u];
            const float* wr = &w1t[(ch0 + u) * 12];
            #pragma unroll
            for (int k = 0; k < 9; k++) a += vin[k] * wr[k];
            y[u] = a; s_own += a;
        }
        s_own += __shfl_xor(s_own, 1, 64);
        float mu = s_own * (1.0f / CH);
        float v_own = 0.f;
        #pragma unroll
        for (int u = 0; u < 20; u++) { float d = y[u] - mu; v_own += d * d; }
        v_own += __shfl_xor(v_own, 1, 64);
        float rs = rsqrtf(v_own * (1.0f / CH) + 1e-6f);
        _Float16 g[20];
        #pragma unroll
        for (int u = 0; u < 20; u++) {
            int ch = ch0 + u;
            g[u] = (_Float16)gelu_fast((y[u] - mu) * rs * p1s[40 + ch] + p1s[80 + ch]);
        }
        const int base = tk * TOKH + (r * 10 + c) * 40 + ch0;
        if (sub == 0) {
            *(v8h*)&x1h[base]      = *(v8h*)&g[0];
            *(v8h*)&x1h[base + 8]  = *(v8h*)&g[8];
            *(v4h*)&x1h[base + 16] = *(v4h*)&g[16];
        } else {
            *(v4h*)&x1h[base]      = *(v4h*)&g[0];
            *(v8h*)&x1h[base + 4]  = *(v8h*)&g[4];
            *(v8h*)&x1h[base + 12] = *(v8h*)&g[12];
        }
    }
    // border fill: rr=8 row (9 pos) + cc=8 col (8 pos) per token, all = z1
    if (t < 34) {
        int tk = (t >= 17), i = t - tk * 17;
        int r = (i < 9) ? 8 : (i - 9);
        int c = (i < 9) ? i : 8;
        const v8h* zsrc = (const v8h*)&ws[Z1_OFF];
        int base = tk * TOKH + (r * 10 + c) * 40;
        *(v8h*)&x1h[base]      = zsrc[0];
        *(v8h*)&x1h[base + 8]  = zsrc[1];
        *(v8h*)&x1h[base + 16] = zsrc[2];
        *(v8h*)&x1h[base + 24] = zsrc[3];
        *(v8h*)&x1h[base + 32] = zsrc[4];
    }
    __syncthreads();

    // ---- Phase C: conv2 MFMA, M=16 real positions/token; wave n owns N-tile n ----
    v4f accA = {0,0,0,0}, accB = {0,0,0,0};
    const int wv   = t >> 6;
    const int lane = t & 63;
    if (wv < 3) {
        const int row = lane & 15;       // A-row = real position index m (p=m>>2,q=m&3)
        const int kg  = lane >> 4;
        const unsigned pbase = (unsigned)((20 * (row >> 2) + 2 * (row & 3)) * 40);
        #pragma unroll
        for (int s = 0; s < 12; s++) {
            const int kc = (s << 2) | kg;
            unsigned aoff = pbase + koff_s[kc];
            v8h a0 = *(const v8h*)&x1h[aoff];
            v8h a1 = *(const v8h*)&x1h[TOKH + aoff];
            v8h bf = *(const v8h*)&ws[(kc * 48 + wv * 16 + row) * 8];
            accA = __builtin_amdgcn_mfma_f32_16x16x32_f16(a0, bf, accA, 0, 0, 0);
            accB = __builtin_amdgcn_mfma_f32_16x16x32_f16(a1, bf, accB, 0, 0, 0);
        }
    }
    __syncthreads();   // x1h reads done; overlay y2

    if (wv < 3) {
        const int cix = lane & 15;           // channel within N-tile
        const int kg  = lane >> 4;
        if (wv < 2 || cix < 8) {             // skip padding channels 40..47
            #pragma unroll
            for (int j = 0; j < 4; j++) {
                int m = (kg << 2) | j;       // real position index
                y2f[m * 48 + wv * 16 + cix]       = accA[j];
                y2f[Y2T + m * 48 + wv * 16 + cix] = accB[j];
            }
        }
    }
    __syncthreads();

    // ---- Phase D: bias + LN2 + gelu + dense over 16 real positions; + const part ----
    if (t < 128) {
        const int tk  = t >> 6;              // wave 0 = token 0, wave 1 = token 1
        const int pos = (t >> 2) & 15;
        const int sub = t & 3;
        const int co0 = sub * 10;
        float vv[10];
        float s_own = 0.f;
        #pragma unroll
        for (int u = 0; u < 10; u++) {
            float a = y2f[tk * Y2T + pos * 48 + co0 + u] + p2s[co0 + u];
            vv[u] = a; s_own += a;
        }
        s_own += __shfl_xor(s_own, 1, 64);
        s_own += __shfl_xor(s_own, 2, 64);
        float mu = s_own * (1.0f / CH);
        float v_own = 0.f;
        #pragma unroll
        for (int u = 0; u < 10; u++) { float d = vv[u] - mu; v_own += d * d; }
        v_own += __shfl_xor(v_own, 1, 64);
        v_own += __shfl_xor(v_own, 2, 64);
        float rs = rsqrtf(v_own * (1.0f / CH) + 1e-6f);

        const int p = pos >> 2, q = pos & 3;
        const float* wp = &dw[((p * 8 + q) * CH + co0) * 6];
        float a6[6] = {0.f, 0.f, 0.f, 0.f, 0.f, 0.f};
        #pragma unroll
        for (int u = 0; u < 10; u++) {
            float gv = gelu_fast((vv[u] - mu) * rs * p2s[40 + co0 + u] + p2s[80 + co0 + u]);
            v2f w01 = *(const v2f*)&wp[u * 6];
            v2f w23 = *(const v2f*)&wp[u * 6 + 2];
            v2f w45 = *(const v2f*)&wp[u * 6 + 4];
            a6[0] += gv * w01[0]; a6[1] += gv * w01[1];
            a6[2] += gv * w23[0]; a6[3] += gv * w23[1];
            a6[4] += gv * w45[0]; a6[5] += gv * w45[1];
        }
        #pragma unroll
        for (int off = 32; off > 0; off >>= 1)
            #pragma unroll
            for (int k = 0; k < 6; k++) a6[k] += __shfl_down(a6[k], off, 64);
        if (lane == 0) {
            const float* oc = (const float*)&ws[OUTC_OFF];
            int f = blockIdx.x * 2 + tk;
            #pragma unroll
            for (int k = 0; k < 6; k++) out[f * 6 + k] = a6[k] + oc[k];
        }
    }
}

extern "C" void kernel_launch(void* const* d_in, const int* in_sizes, int n_in,
                              void* d_out, int out_size, void* d_ws, size_t ws_size,
                              hipStream_t stream) {
    const float* img = (const float*)d_in[0];
    // d_in[1] = masks: analytically redundant (mask == cell id), not read.
    const float* w1  = (const float*)d_in[2];
    const float* b1  = (const float*)d_in[3];
    const float* s1  = (const float*)d_in[4];
    const float* bb1 = (const float*)d_in[5];
    const float* w2  = (const float*)d_in[6];
    const float* b2  = (const float*)d_in[7];
    const float* s2  = (const float*)d_in[8];
    const float* bb2 = (const float*)d_in[9];
    const float* dw  = (const float*)d_in[10];
    const float* db  = (const float*)d_in[11];
    float* out = (float*)d_out;
    _Float16* ws = (_Float16*)d_ws;

    prep_kernel<<<32, 256, 0, stream>>>(w2, b1, s1, bb1, b2, s2, bb2, dw, db, ws);
    sgn_kernel<<<2048, 256, 0, stream>>>(img, w1, b1, s1, bb1,
                                         b2, s2, bb2, dw, ws, out);
}